// Round 10
// baseline (10177.574 us; speedup 1.0000x reference)
//
#include <hip/hip_runtime.h>
#include <stdint.h>

#define B_  256
#define S_  512
#define D_  64
#define H_  256
#define G3_ 768

typedef __attribute__((ext_vector_type(8))) short s8v;   // 8 bf16 (4 VGPRs)
typedef __attribute__((ext_vector_type(4))) short s4v;   // 4 bf16 (2 VGPRs)
typedef __attribute__((ext_vector_type(4))) float f4v;   // MFMA accumulator
typedef __attribute__((ext_vector_type(4))) float f4r;   // raw float4 (NT-capable)

#define MF(a, b, c) __builtin_amdgcn_mfma_f32_16x16x32_bf16((a), (b), (c), 0, 0, 0)

__device__ __forceinline__ unsigned short f2bf(float x) {  // RNE
  unsigned u = __float_as_uint(x);
  unsigned r = (u + 0x7fffu + ((u >> 16) & 1u)) >> 16;
  return (unsigned short)r;
}
__device__ __forceinline__ float bf2f(unsigned short s) {
  return __uint_as_float(((unsigned)s) << 16);
}
__device__ __forceinline__ float sigm(float x) {
  return __builtin_amdgcn_rcpf(1.f + __expf(-x));
}
__device__ __forceinline__ float tanh_f(float x) {
  return 1.f - 2.f * __builtin_amdgcn_rcpf(1.f + __expf(2.f * x));
}

// ---------------------------------------------------------------------------
// MFMA bf16-split input GEMM (3-pass, fp32-class accuracy; unchanged).
// ---------------------------------------------------------------------------
__global__ __launch_bounds__(256) void gemm_mfma(
    const float* __restrict__ A, const float* __restrict__ W,
    const float* __restrict__ bias, float* __restrict__ C,
    int K, int chsh, int t0)
{
  const int g0 = blockIdx.x * 64;
  const int r0 = blockIdx.y * 64;
  const int tid = threadIdx.x;
  const int w = tid >> 6, l = tid & 63;
  const int fr = l & 15, fq = l >> 4;

  __shared__ unsigned short Ah[64][40], Al[64][40];
  __shared__ unsigned short Wh[64][40], Wl[64][40];

  f4v acc[4] = {};

  const int row = tid >> 2, q = tid & 3;
  const int CHm1 = (1 << chsh) - 1;
  const int r = r0 + row;
  const int rg = ((r >> chsh) * S_) + t0 + (r & CHm1);
  const float* ap = A + (size_t)rg * K + q * 8;
  const float* wp = W + (size_t)(g0 + row) * K + q * 8;

  for (int k0 = 0; k0 < K; k0 += 32) {
    float4 a0 = *(const float4*)(ap + k0);
    float4 a1 = *(const float4*)(ap + k0 + 4);
    float4 w0 = *(const float4*)(wp + k0);
    float4 w1 = *(const float4*)(wp + k0 + 4);
    __syncthreads();
    float av[8] = {a0.x,a0.y,a0.z,a0.w,a1.x,a1.y,a1.z,a1.w};
    float wv[8] = {w0.x,w0.y,w0.z,w0.w,w1.x,w1.y,w1.z,w1.w};
    unsigned short ah[8], al_[8], wh[8], wl_[8];
    #pragma unroll
    for (int i = 0; i < 8; ++i) {
      ah[i]  = f2bf(av[i]);  al_[i] = f2bf(av[i] - bf2f(ah[i]));
      wh[i]  = f2bf(wv[i]);  wl_[i] = f2bf(wv[i] - bf2f(wh[i]));
    }
    *(s8v*)&Ah[row][q*8] = *(s8v*)ah;  *(s8v*)&Al[row][q*8] = *(s8v*)al_;
    *(s8v*)&Wh[row][q*8] = *(s8v*)wh;  *(s8v*)&Wl[row][q*8] = *(s8v*)wl_;
    __syncthreads();

    s8v a_hi = *(const s8v*)&Ah[w*16 + fr][fq*8];
    s8v a_lo = *(const s8v*)&Al[w*16 + fr][fq*8];
    #pragma unroll
    for (int c = 0; c < 4; ++c) {
      s8v b_hi = *(const s8v*)&Wh[c*16 + fr][fq*8];
      s8v b_lo = *(const s8v*)&Wl[c*16 + fr][fq*8];
      acc[c] = MF(a_hi, b_hi, acc[c]);
      acc[c] = MF(a_lo, b_hi, acc[c]);
      acc[c] = MF(a_hi, b_lo, acc[c]);
    }
  }

  const int orow = r0 + w * 16 + fq * 4;
  #pragma unroll
  for (int c = 0; c < 4; ++c) {
    const float bi = bias[g0 + c * 16 + fr];
    #pragma unroll
    for (int i = 0; i < 4; ++i) {
      float v = acc[c][i] + bi;
      __builtin_nontemporal_store(v, &C[(size_t)(orow + i) * G3_ + g0 + c * 16 + fr]);
    }
  }
}

// ---------------------------------------------------------------------------
// Pack W_hh into MFMA fragment order, bf16-hi only.
// ---------------------------------------------------------------------------
__global__ __launch_bounds__(64) void pack_whh(
    const float* __restrict__ Whh, unsigned short* __restrict__ Whp)
{
  const int gti = blockIdx.x, kc = blockIdx.y, lane = threadIdx.x;
  const int row = gti * 16 + (lane & 15);
  const int k0  = kc * 32 + (lane >> 4) * 8;
  const float* src = &Whh[(size_t)row * H_ + k0];
  unsigned short hi8[8];
  #pragma unroll
  for (int s = 0; s < 8; ++s) hi8[s] = f2bf(src[s]);
  const size_t o = ((size_t)(gti * 8 + kc) * 64 + lane) * 8;
  *(s8v*)&Whp[o] = *(s8v*)hi8;
}

__global__ __launch_bounds__(768) void bias2_k(
    const float* __restrict__ bih, const float* __restrict__ bhh,
    float* __restrict__ bias2)
{
  int g = threadIdx.x;
  bias2[g] = bih[g] + (g < 512 ? bhh[g] : 0.f);
}

// ---------------------------------------------------------------------------
// MFMA GRU scan v5: all-resident W-hi in VGPR/AGPR (r,z,n = 96 regs), h state
// fp32 in registers, single bf16 A-pass (3 MFMA/kc). LDS: Ahh 8KB + ystage
// 16KB = 24KB. 2 barriers/step. y flushed via coalesced transpose from
// ystage. Zero cross-WG sync; 16 WGs x 1024 threads.
// ---------------------------------------------------------------------------
__global__ __launch_bounds__(1024, 4) void gru_scan(
    const float* __restrict__ gx, const unsigned short* __restrict__ Whp,
    const float* __restrict__ bhh, float* __restrict__ hbuf,
    float* __restrict__ y, int CH, int t0c, int last)
{
  const int bid = blockIdx.x;          // 16
  const int b0  = bid * 16;
  const int tid = threadIdx.x;
  const int wid = tid >> 6, lane = tid & 63;
  const int bb = lane & 15;            // batch-local (D col)
  const int fq = lane >> 4;            // row quad (D rows 4fq..4fq+3)

  __shared__ unsigned short Ahh[8 * 512];   // [8 kc][512] = 8KB
  __shared__ float ystage[16 * 256];        // [16 bb][256 u] = 16KB, swizzled

  const s8v* WhpV = (const s8v*)Whp;

  // resident W-hi tiles: r, z, n (96 regs; compiler places in VGPR/AGPR)
  s8v whr[8], whz[8], whn[8];
  #pragma unroll
  for (int kc = 0; kc < 8; ++kc) {
    whr[kc] = WhpV[((     wid) * 8 + kc) * 64 + lane];
    whz[kc] = WhpV[((16 + wid) * 8 + kc) * 64 + lane];
    whn[kc] = WhpV[((32 + wid) * 8 + kc) * 64 + lane];
  }

  const int u0 = 16 * wid + 4 * fq;        // own unit quad
  const int sw = (bb & 7) << 2;            // ystage bank swizzle (4-float gran)

  const f4r bhn4 = *(const f4r*)&bhh[2 * H_ + u0];

  // h state in registers + seed ystage for builders
  f4r hn4 = {0.f, 0.f, 0.f, 0.f};
  if (t0c != 0) hn4 = *(const f4r*)&hbuf[(size_t)(b0 + bb) * H_ + u0];
  *(f4r*)&ystage[bb * 256 + (u0 ^ sw)] = hn4;

  // builder role: wave pair (2k,2k+1) builds k-chunk k, halves sh=0/1
  const int kc_b = wid >> 1;
  const int sh   = wid & 1;
  const int ub   = 32 * kc_b + 8 * fq + 4 * sh;   // u-quad this thread packs

  // coalesced y-flush mapping: thread -> (row, 4 consecutive units)
  const int frow = tid >> 6;                // 16 rows (batches)
  const int fcol = (tid & 63) << 2;         // 0..252
  const int fsw  = (frow & 7) << 2;

  for (int t = 0; t < CH; ++t) {
    __syncthreads();   // bar0: ystage holds h(t-1) from all waves

    // coalesced y flush of step t-1 (wave stores contiguous 1KB)
    if (!last && t > 0) {
      f4r v = *(const f4r*)&ystage[frow * 256 + (fcol ^ fsw)];
      __builtin_nontemporal_store(
          v, (f4r*)&y[((size_t)(b0 + frow) * S_ + (t0c + t - 1)) * H_ + fcol]);
    }

    // gx loads early (latency hides under builder + bar1 + MFMA loop)
    const float* gb = gx + ((size_t)(b0 + bb) * CH + t) * G3_;
    f4r xr4 = __builtin_nontemporal_load((const f4r*)(gb + u0));
    f4r xz4 = __builtin_nontemporal_load((const f4r*)(gb + H_ + u0));
    f4r xn4 = __builtin_nontemporal_load((const f4r*)(gb + 2 * H_ + u0));

    // builder: bf16(h) A-frag half k-chunk
    {
      f4r hv = *(const f4r*)&ystage[bb * 256 + (ub ^ sw)];
      s4v hh;
      #pragma unroll
      for (int j = 0; j < 4; ++j) hh[j] = (short)f2bf(hv[j]);
      *(s4v*)&Ahh[kc_b * 512 + lane * 8 + 4 * sh] = hh;
    }

    __syncthreads();   // bar1: A-frags visible

    f4v accR = {}, accZ = {}, accN = {};
    #pragma unroll
    for (int kc = 0; kc < 8; ++kc) {
      s8v ahh = *(const s8v*)&Ahh[kc * 512 + lane * 8];
      accR = MF(whr[kc], ahh, accR);
      accZ = MF(whz[kc], ahh, accZ);
      accN = MF(whn[kc], ahh, accN);
    }

    // epilogue: gate math on register h; write new h to ystage for builders
    #pragma unroll
    for (int i = 0; i < 4; ++i) {
      const float r = sigm(xr4[i] + accR[i]);
      const float z = sigm(xz4[i] + accZ[i]);
      const float n = tanh_f(xn4[i] + r * (accN[i] + bhn4[i]));
      hn4[i] = (1.f - z) * n + z * hn4[i];
    }
    *(f4r*)&ystage[bb * 256 + (u0 ^ sw)] = hn4;
  }

  // tail: flush final y row + persist h
  __syncthreads();
  if (!last) {
    f4r v = *(const f4r*)&ystage[frow * 256 + (fcol ^ fsw)];
    __builtin_nontemporal_store(
        v, (f4r*)&y[((size_t)(b0 + frow) * S_ + (t0c + CH - 1)) * H_ + fcol]);
  }
  *(f4r*)&hbuf[(size_t)(b0 + bb) * H_ + u0] = hn4;
}

// ---------------------------------------------------------------------------
// Head: LayerNorm(h_last) -> MLP 256->32 (ReLU) -> 32->1. One wave per batch.
// ---------------------------------------------------------------------------
__global__ __launch_bounds__(64) void head_kernel(
    const float* __restrict__ hlast, const float* __restrict__ lng,
    const float* __restrict__ lnb, const float* __restrict__ W1,
    const float* __restrict__ b1, const float* __restrict__ W2,
    const float* __restrict__ b2, float* __restrict__ out)
{
  const int b = blockIdx.x;
  const int lane = threadIdx.x;
  float4 v = *(const float4*)&hlast[(size_t)b * H_ + lane * 4];
  float s = v.x + v.y + v.z + v.w;
  #pragma unroll
  for (int m = 32; m > 0; m >>= 1) s += __shfl_xor(s, m, 64);
  const float mu = s * (1.f / 256.f);
  const float dx = v.x - mu, dy = v.y - mu, dz = v.z - mu, dw = v.w - mu;
  float q = dx*dx + dy*dy + dz*dz + dw*dw;
  #pragma unroll
  for (int m = 32; m > 0; m >>= 1) q += __shfl_xor(q, m, 64);
  const float rstd = rsqrtf(q * (1.f / 256.f) + 1e-5f);

  __shared__ float ln[256];
  const int i4 = lane * 4;
  ln[i4 + 0] = dx * rstd * lng[i4 + 0] + lnb[i4 + 0];
  ln[i4 + 1] = dy * rstd * lng[i4 + 1] + lnb[i4 + 1];
  ln[i4 + 2] = dz * rstd * lng[i4 + 2] + lnb[i4 + 2];
  ln[i4 + 3] = dw * rstd * lng[i4 + 3] + lnb[i4 + 3];
  __syncthreads();

  float hd = 0.f;
  if (lane < 32) {
    const float* w = W1 + (size_t)lane * H_;
    float a = 0.f;
    for (int k = 0; k < H_; ++k) a += ln[k] * w[k];
    a += b1[lane];
    hd = fmaxf(a, 0.f) * W2[lane];
  }
  #pragma unroll
  for (int m = 16; m > 0; m >>= 1) hd += __shfl_xor(hd, m, 64);
  if (lane == 0) out[b] = hd + b2[0];
}

// ---------------------------------------------------------------------------
extern "C" void kernel_launch(void* const* d_in, const int* in_sizes, int n_in,
                              void* d_out, int out_size, void* d_ws, size_t ws_size,
                              hipStream_t stream)
{
  const float* x     = (const float*)d_in[0];
  const float* W_ih0 = (const float*)d_in[1];
  const float* W_ihr = (const float*)d_in[2];
  const float* W_hh  = (const float*)d_in[3];
  const float* b_ih  = (const float*)d_in[4];
  const float* b_hh  = (const float*)d_in[5];
  const float* lng   = (const float*)d_in[6];
  const float* lnb   = (const float*)d_in[7];
  const float* W1    = (const float*)d_in[8];
  const float* b1    = (const float*)d_in[9];
  const float* W2    = (const float*)d_in[10];
  const float* b2    = (const float*)d_in[11];
  float* out = (float*)d_out;

  const size_t y_elems   = (size_t)B_ * S_ * H_;       // 134 MB
  const size_t h_elems   = (size_t)B_ * H_;
  const size_t whp_elems = (size_t)G3_ * H_;           // bf16-hi pack

  int CH = 512;
  while (CH > 64) {
    size_t need = (y_elems + (size_t)B_ * CH * G3_ + h_elems + 768) * 4
                + whp_elems * 2 + 4096;
    if (need <= ws_size) break;
    CH >>= 1;
  }
  const int chsh = __builtin_ctz((unsigned)CH);

  float* y    = (float*)d_ws;
  float* gx   = y + y_elems;
  float* hbuf = gx + (size_t)B_ * CH * G3_;
  unsigned short* Whp = (unsigned short*)(hbuf + h_elems);
  float* bias2 = (float*)(Whp + whp_elems);

  for (int l = 0; l < 3; ++l) {
    const float* Wih   = (l == 0) ? W_ih0 : (W_ihr + (size_t)(l - 1) * G3_ * H_);
    const int    K     = (l == 0) ? D_ : H_;
    const float* A     = (l == 0) ? x : y;
    const float* Whh_l = W_hh + (size_t)l * G3_ * H_;
    const float* bih_l = b_ih + (size_t)l * G3_;
    const float* bhh_l = b_hh + (size_t)l * G3_;
    const int last = (l == 2) ? 1 : 0;

    bias2_k<<<1, 768, 0, stream>>>(bih_l, bhh_l, bias2);
    pack_whh<<<dim3(48, 8), 64, 0, stream>>>(Whh_l, Whp);

    for (int t0 = 0; t0 < S_; t0 += CH) {
      gemm_mfma<<<dim3(G3_ / 64, (B_ * CH) / 64), 256, 0, stream>>>(
          A, Wih, bias2, gx, K, chsh, t0);
      gru_scan<<<16, 1024, 0, stream>>>(
          gx, Whp, bhh_l, hbuf, y, CH, t0, last);
    }
  }

  head_kernel<<<256, 64, 0, stream>>>(hbuf, lng, lnb, W1, b1, W2, b2, out);
}

// Round 11
// 4961.479 us; speedup vs baseline: 2.0513x; 2.0513x over previous
//
#include <hip/hip_runtime.h>
#include <stdint.h>

#define B_  256
#define S_  512
#define D_  64
#define H_  256
#define G3_ 768

typedef __attribute__((ext_vector_type(8))) short s8v;   // 8 bf16 (4 VGPRs)
typedef __attribute__((ext_vector_type(4))) short s4v;   // 4 bf16 (2 VGPRs)
typedef __attribute__((ext_vector_type(4))) float f4v;   // MFMA accumulator
typedef __attribute__((ext_vector_type(4))) float f4r;   // raw float4 (NT-capable)

#define MF(a, b, c) __builtin_amdgcn_mfma_f32_16x16x32_bf16((a), (b), (c), 0, 0, 0)

__device__ __forceinline__ unsigned short f2bf(float x) {  // RNE
  unsigned u = __float_as_uint(x);
  unsigned r = (u + 0x7fffu + ((u >> 16) & 1u)) >> 16;
  return (unsigned short)r;
}
__device__ __forceinline__ float bf2f(unsigned short s) {
  return __uint_as_float(((unsigned)s) << 16);
}
__device__ __forceinline__ float sigm(float x) {
  return __builtin_amdgcn_rcpf(1.f + __expf(-x));
}
__device__ __forceinline__ float tanh_f(float x) {
  return 1.f - 2.f * __builtin_amdgcn_rcpf(1.f + __expf(2.f * x));
}

// ---------------------------------------------------------------------------
// MFMA bf16-split input GEMM (3-pass, fp32-class accuracy; unchanged).
// ---------------------------------------------------------------------------
__global__ __launch_bounds__(256) void gemm_mfma(
    const float* __restrict__ A, const float* __restrict__ W,
    const float* __restrict__ bias, float* __restrict__ C,
    int K, int chsh, int t0)
{
  const int g0 = blockIdx.x * 64;
  const int r0 = blockIdx.y * 64;
  const int tid = threadIdx.x;
  const int w = tid >> 6, l = tid & 63;
  const int fr = l & 15, fq = l >> 4;

  __shared__ unsigned short Ah[64][40], Al[64][40];
  __shared__ unsigned short Wh[64][40], Wl[64][40];

  f4v acc[4] = {};

  const int row = tid >> 2, q = tid & 3;
  const int CHm1 = (1 << chsh) - 1;
  const int r = r0 + row;
  const int rg = ((r >> chsh) * S_) + t0 + (r & CHm1);
  const float* ap = A + (size_t)rg * K + q * 8;
  const float* wp = W + (size_t)(g0 + row) * K + q * 8;

  for (int k0 = 0; k0 < K; k0 += 32) {
    float4 a0 = *(const float4*)(ap + k0);
    float4 a1 = *(const float4*)(ap + k0 + 4);
    float4 w0 = *(const float4*)(wp + k0);
    float4 w1 = *(const float4*)(wp + k0 + 4);
    __syncthreads();
    float av[8] = {a0.x,a0.y,a0.z,a0.w,a1.x,a1.y,a1.z,a1.w};
    float wv[8] = {w0.x,w0.y,w0.z,w0.w,w1.x,w1.y,w1.z,w1.w};
    unsigned short ah[8], al_[8], wh[8], wl_[8];
    #pragma unroll
    for (int i = 0; i < 8; ++i) {
      ah[i]  = f2bf(av[i]);  al_[i] = f2bf(av[i] - bf2f(ah[i]));
      wh[i]  = f2bf(wv[i]);  wl_[i] = f2bf(wv[i] - bf2f(wh[i]));
    }
    *(s8v*)&Ah[row][q*8] = *(s8v*)ah;  *(s8v*)&Al[row][q*8] = *(s8v*)al_;
    *(s8v*)&Wh[row][q*8] = *(s8v*)wh;  *(s8v*)&Wl[row][q*8] = *(s8v*)wl_;
    __syncthreads();

    s8v a_hi = *(const s8v*)&Ah[w*16 + fr][fq*8];
    s8v a_lo = *(const s8v*)&Al[w*16 + fr][fq*8];
    #pragma unroll
    for (int c = 0; c < 4; ++c) {
      s8v b_hi = *(const s8v*)&Wh[c*16 + fr][fq*8];
      s8v b_lo = *(const s8v*)&Wl[c*16 + fr][fq*8];
      acc[c] = MF(a_hi, b_hi, acc[c]);
      acc[c] = MF(a_lo, b_hi, acc[c]);
      acc[c] = MF(a_hi, b_lo, acc[c]);
    }
  }

  const int orow = r0 + w * 16 + fq * 4;
  #pragma unroll
  for (int c = 0; c < 4; ++c) {
    const float bi = bias[g0 + c * 16 + fr];
    #pragma unroll
    for (int i = 0; i < 4; ++i) {
      float v = acc[c][i] + bi;
      __builtin_nontemporal_store(v, &C[(size_t)(orow + i) * G3_ + g0 + c * 16 + fr]);
    }
  }
}

// ---------------------------------------------------------------------------
// Pack W_hh into MFMA fragment order, bf16-hi only.
// ---------------------------------------------------------------------------
__global__ __launch_bounds__(64) void pack_whh(
    const float* __restrict__ Whh, unsigned short* __restrict__ Whp)
{
  const int gti = blockIdx.x, kc = blockIdx.y, lane = threadIdx.x;
  const int row = gti * 16 + (lane & 15);
  const int k0  = kc * 32 + (lane >> 4) * 8;
  const float* src = &Whh[(size_t)row * H_ + k0];
  unsigned short hi8[8];
  #pragma unroll
  for (int s = 0; s < 8; ++s) hi8[s] = f2bf(src[s]);
  const size_t o = ((size_t)(gti * 8 + kc) * 64 + lane) * 8;
  *(s8v*)&Whp[o] = *(s8v*)hi8;
}

__global__ __launch_bounds__(768) void bias2_k(
    const float* __restrict__ bih, const float* __restrict__ bhh,
    float* __restrict__ bias2)
{
  int g = threadIdx.x;
  bias2[g] = bih[g] + (g < 512 ? bhh[g] : 0.f);
}

// ---------------------------------------------------------------------------
// MFMA GRU scan v6: R9 resource placement (r,z-hi in 64 regs -> fits the
// 128-reg/wave cap at 16 waves/CU; n-hi in LDS 128KB) + single bf16 A-pass
// (3 MFMA/kc, no Ahl) + h fp32 in registers + coalesced y-flush.
// LDS: WhN 128KB + Ahh 8KB + ystage 16KB = 152KB. 2 barriers/step.
// 16 WGs x 1024 threads; zero cross-WG sync, zero W stream.
// ---------------------------------------------------------------------------
__global__ __launch_bounds__(1024, 4) void gru_scan(
    const float* __restrict__ gx, const unsigned short* __restrict__ Whp,
    const float* __restrict__ bhh, float* __restrict__ hbuf,
    float* __restrict__ y, int CH, int t0c, int last)
{
  const int bid = blockIdx.x;          // 16
  const int b0  = bid * 16;
  const int tid = threadIdx.x;
  const int wid = tid >> 6, lane = tid & 63;
  const int bb = lane & 15;            // batch-local (D col)
  const int fq = lane >> 4;            // row quad (D rows 4fq..4fq+3)

  extern __shared__ unsigned short lds_[];
  unsigned short* WhN = lds_;                       // [16 w][8 kc][512] = 128KB
  unsigned short* Ahh = lds_ + 65536;               // [8 kc][512] = 8KB
  float* ystage = (float*)(Ahh + 4096);             // [16 bb][256 u] = 16KB, swz

  const s8v* WhpV = (const s8v*)Whp;

  // resident r-hi, z-hi tiles (64 regs -> within the 128/wave cap)
  s8v whr[8], whz[8];
  #pragma unroll
  for (int kc = 0; kc < 8; ++kc) {
    whr[kc] = WhpV[((     wid) * 8 + kc) * 64 + lane];
    whz[kc] = WhpV[((16 + wid) * 8 + kc) * 64 + lane];
  }
  // n-hi tile -> LDS (each wave its own 8KB region)
  #pragma unroll
  for (int kc = 0; kc < 8; ++kc) {
    s8v v = WhpV[((32 + wid) * 8 + kc) * 64 + lane];
    *(s8v*)&WhN[(wid * 8 + kc) * 512 + lane * 8] = v;
  }

  const int u0 = 16 * wid + 4 * fq;        // own unit quad
  const int sw = (bb & 7) << 2;            // ystage bank swizzle (4-float gran)

  const f4r bhn4 = *(const f4r*)&bhh[2 * H_ + u0];

  // h state in registers + seed ystage for builders
  f4r hn4 = {0.f, 0.f, 0.f, 0.f};
  if (t0c != 0) hn4 = *(const f4r*)&hbuf[(size_t)(b0 + bb) * H_ + u0];
  *(f4r*)&ystage[bb * 256 + (u0 ^ sw)] = hn4;

  // builder role: wave pair (2k,2k+1) builds k-chunk k, halves sh=0/1
  const int kc_b = wid >> 1;
  const int sh   = wid & 1;
  const int ub   = 32 * kc_b + 8 * fq + 4 * sh;   // u-quad this thread packs

  // coalesced y-flush mapping: thread -> (row, 4 consecutive units)
  const int frow = tid >> 6;                // 16 rows (batches)
  const int fcol = (tid & 63) << 2;         // 0..252
  const int fsw  = (frow & 7) << 2;

  for (int t = 0; t < CH; ++t) {
    __syncthreads();   // bar0: ystage holds h(t-1) from all waves

    // coalesced y flush of step t-1 (wave stores contiguous 1KB)
    if (!last && t > 0) {
      f4r v = *(const f4r*)&ystage[frow * 256 + (fcol ^ fsw)];
      __builtin_nontemporal_store(
          v, (f4r*)&y[((size_t)(b0 + frow) * S_ + (t0c + t - 1)) * H_ + fcol]);
    }

    // gx loads early (latency hides under builder + bar1 + MFMA loop)
    const float* gb = gx + ((size_t)(b0 + bb) * CH + t) * G3_;
    f4r xr4 = __builtin_nontemporal_load((const f4r*)(gb + u0));
    f4r xz4 = __builtin_nontemporal_load((const f4r*)(gb + H_ + u0));
    f4r xn4 = __builtin_nontemporal_load((const f4r*)(gb + 2 * H_ + u0));

    // builder: bf16(h) A-frag half k-chunk
    {
      f4r hv = *(const f4r*)&ystage[bb * 256 + (ub ^ sw)];
      s4v hh;
      #pragma unroll
      for (int j = 0; j < 4; ++j) hh[j] = (short)f2bf(hv[j]);
      *(s4v*)&Ahh[kc_b * 512 + lane * 8 + 4 * sh] = hh;
    }

    __syncthreads();   // bar1: A-frags visible

    f4v accR = {}, accZ = {}, accN = {};
    #pragma unroll
    for (int kc = 0; kc < 8; ++kc) {
      s8v ahh = *(const s8v*)&Ahh[kc * 512 + lane * 8];
      s8v wn  = *(const s8v*)&WhN[(wid * 8 + kc) * 512 + lane * 8];
      accR = MF(whr[kc], ahh, accR);
      accZ = MF(whz[kc], ahh, accZ);
      accN = MF(wn,      ahh, accN);
    }

    // epilogue: gate math on register h; write new h to ystage for builders
    #pragma unroll
    for (int i = 0; i < 4; ++i) {
      const float r = sigm(xr4[i] + accR[i]);
      const float z = sigm(xz4[i] + accZ[i]);
      const float n = tanh_f(xn4[i] + r * (accN[i] + bhn4[i]));
      hn4[i] = (1.f - z) * n + z * hn4[i];
    }
    *(f4r*)&ystage[bb * 256 + (u0 ^ sw)] = hn4;
  }

  // tail: flush final y row + persist h
  __syncthreads();
  if (!last) {
    f4r v = *(const f4r*)&ystage[frow * 256 + (fcol ^ fsw)];
    __builtin_nontemporal_store(
        v, (f4r*)&y[((size_t)(b0 + frow) * S_ + (t0c + CH - 1)) * H_ + fcol]);
  }
  *(f4r*)&hbuf[(size_t)(b0 + bb) * H_ + u0] = hn4;
}

// ---------------------------------------------------------------------------
// Head: LayerNorm(h_last) -> MLP 256->32 (ReLU) -> 32->1. One wave per batch.
// ---------------------------------------------------------------------------
__global__ __launch_bounds__(64) void head_kernel(
    const float* __restrict__ hlast, const float* __restrict__ lng,
    const float* __restrict__ lnb, const float* __restrict__ W1,
    const float* __restrict__ b1, const float* __restrict__ W2,
    const float* __restrict__ b2, float* __restrict__ out)
{
  const int b = blockIdx.x;
  const int lane = threadIdx.x;
  float4 v = *(const float4*)&hlast[(size_t)b * H_ + lane * 4];
  float s = v.x + v.y + v.z + v.w;
  #pragma unroll
  for (int m = 32; m > 0; m >>= 1) s += __shfl_xor(s, m, 64);
  const float mu = s * (1.f / 256.f);
  const float dx = v.x - mu, dy = v.y - mu, dz = v.z - mu, dw = v.w - mu;
  float q = dx*dx + dy*dy + dz*dz + dw*dw;
  #pragma unroll
  for (int m = 32; m > 0; m >>= 1) q += __shfl_xor(q, m, 64);
  const float rstd = rsqrtf(q * (1.f / 256.f) + 1e-5f);

  __shared__ float ln[256];
  const int i4 = lane * 4;
  ln[i4 + 0] = dx * rstd * lng[i4 + 0] + lnb[i4 + 0];
  ln[i4 + 1] = dy * rstd * lng[i4 + 1] + lnb[i4 + 1];
  ln[i4 + 2] = dz * rstd * lng[i4 + 2] + lnb[i4 + 2];
  ln[i4 + 3] = dw * rstd * lng[i4 + 3] + lnb[i4 + 3];
  __syncthreads();

  float hd = 0.f;
  if (lane < 32) {
    const float* w = W1 + (size_t)lane * H_;
    float a = 0.f;
    for (int k = 0; k < H_; ++k) a += ln[k] * w[k];
    a += b1[lane];
    hd = fmaxf(a, 0.f) * W2[lane];
  }
  #pragma unroll
  for (int m = 16; m > 0; m >>= 1) hd += __shfl_xor(hd, m, 64);
  if (lane == 0) out[b] = hd + b2[0];
}

// ---------------------------------------------------------------------------
extern "C" void kernel_launch(void* const* d_in, const int* in_sizes, int n_in,
                              void* d_out, int out_size, void* d_ws, size_t ws_size,
                              hipStream_t stream)
{
  const float* x     = (const float*)d_in[0];
  const float* W_ih0 = (const float*)d_in[1];
  const float* W_ihr = (const float*)d_in[2];
  const float* W_hh  = (const float*)d_in[3];
  const float* b_ih  = (const float*)d_in[4];
  const float* b_hh  = (const float*)d_in[5];
  const float* lng   = (const float*)d_in[6];
  const float* lnb   = (const float*)d_in[7];
  const float* W1    = (const float*)d_in[8];
  const float* b1    = (const float*)d_in[9];
  const float* W2    = (const float*)d_in[10];
  const float* b2    = (const float*)d_in[11];
  float* out = (float*)d_out;

  const size_t y_elems   = (size_t)B_ * S_ * H_;       // 134 MB
  const size_t h_elems   = (size_t)B_ * H_;
  const size_t whp_elems = (size_t)G3_ * H_;           // bf16-hi pack

  int CH = 512;
  while (CH > 64) {
    size_t need = (y_elems + (size_t)B_ * CH * G3_ + h_elems + 768) * 4
                + whp_elems * 2 + 4096;
    if (need <= ws_size) break;
    CH >>= 1;
  }
  const int chsh = __builtin_ctz((unsigned)CH);

  float* y    = (float*)d_ws;
  float* gx   = y + y_elems;
  float* hbuf = gx + (size_t)B_ * CH * G3_;
  unsigned short* Whp = (unsigned short*)(hbuf + h_elems);
  float* bias2 = (float*)(Whp + whp_elems);

  const size_t lds_bytes = 131072 + 8192 + 16384;   // 152 KiB

  for (int l = 0; l < 3; ++l) {
    const float* Wih   = (l == 0) ? W_ih0 : (W_ihr + (size_t)(l - 1) * G3_ * H_);
    const int    K     = (l == 0) ? D_ : H_;
    const float* A     = (l == 0) ? x : y;
    const float* Whh_l = W_hh + (size_t)l * G3_ * H_;
    const float* bih_l = b_ih + (size_t)l * G3_;
    const float* bhh_l = b_hh + (size_t)l * G3_;
    const int last = (l == 2) ? 1 : 0;

    bias2_k<<<1, 768, 0, stream>>>(bih_l, bhh_l, bias2);
    pack_whh<<<dim3(48, 8), 64, 0, stream>>>(Whh_l, Whp);

    for (int t0 = 0; t0 < S_; t0 += CH) {
      gemm_mfma<<<dim3(G3_ / 64, (B_ * CH) / 64), 256, 0, stream>>>(
          A, Wih, bias2, gx, K, chsh, t0);
      gru_scan<<<16, 1024, lds_bytes, stream>>>(
          gx, Whp, bhh_l, hbuf, y, CH, t0, last);
    }
  }

  head_kernel<<<256, 64, 0, stream>>>(hbuf, lng, lnb, W1, b1, W2, b2, out);
}

// Round 12
// 4873.109 us; speedup vs baseline: 2.0885x; 1.0181x over previous
//
#include <hip/hip_runtime.h>
#include <stdint.h>

#define B_  256
#define S_  512
#define D_  64
#define H_  256
#define G3_ 768

typedef __attribute__((ext_vector_type(8))) short s8v;   // 8 bf16 (4 VGPRs)
typedef __attribute__((ext_vector_type(4))) short s4v;   // 4 bf16 (2 VGPRs)
typedef __attribute__((ext_vector_type(4))) float f4v;   // MFMA accumulator
typedef __attribute__((ext_vector_type(4))) float f4r;   // raw float4 (NT-capable)

#define MF(a, b, c) __builtin_amdgcn_mfma_f32_16x16x32_bf16((a), (b), (c), 0, 0, 0)

__device__ __forceinline__ unsigned short f2bf(float x) {  // RNE
  unsigned u = __float_as_uint(x);
  unsigned r = (u + 0x7fffu + ((u >> 16) & 1u)) >> 16;
  return (unsigned short)r;
}
__device__ __forceinline__ float bf2f(unsigned short s) {
  return __uint_as_float(((unsigned)s) << 16);
}
__device__ __forceinline__ float sigm(float x) {
  return __builtin_amdgcn_rcpf(1.f + __expf(-x));
}
__device__ __forceinline__ float tanh_f(float x) {
  return 1.f - 2.f * __builtin_amdgcn_rcpf(1.f + __expf(2.f * x));
}

// ---------------------------------------------------------------------------
// MFMA bf16-split input GEMM (3-pass, fp32-class accuracy; unchanged).
// ---------------------------------------------------------------------------
__global__ __launch_bounds__(256) void gemm_mfma(
    const float* __restrict__ A, const float* __restrict__ W,
    const float* __restrict__ bias, float* __restrict__ C,
    int K, int chsh, int t0)
{
  const int g0 = blockIdx.x * 64;
  const int r0 = blockIdx.y * 64;
  const int tid = threadIdx.x;
  const int w = tid >> 6, l = tid & 63;
  const int fr = l & 15, fq = l >> 4;

  __shared__ unsigned short Ah[64][40], Al[64][40];
  __shared__ unsigned short Wh[64][40], Wl[64][40];

  f4v acc[4] = {};

  const int row = tid >> 2, q = tid & 3;
  const int CHm1 = (1 << chsh) - 1;
  const int r = r0 + row;
  const int rg = ((r >> chsh) * S_) + t0 + (r & CHm1);
  const float* ap = A + (size_t)rg * K + q * 8;
  const float* wp = W + (size_t)(g0 + row) * K + q * 8;

  for (int k0 = 0; k0 < K; k0 += 32) {
    float4 a0 = *(const float4*)(ap + k0);
    float4 a1 = *(const float4*)(ap + k0 + 4);
    float4 w0 = *(const float4*)(wp + k0);
    float4 w1 = *(const float4*)(wp + k0 + 4);
    __syncthreads();
    float av[8] = {a0.x,a0.y,a0.z,a0.w,a1.x,a1.y,a1.z,a1.w};
    float wv[8] = {w0.x,w0.y,w0.z,w0.w,w1.x,w1.y,w1.z,w1.w};
    unsigned short ah[8], al_[8], wh[8], wl_[8];
    #pragma unroll
    for (int i = 0; i < 8; ++i) {
      ah[i]  = f2bf(av[i]);  al_[i] = f2bf(av[i] - bf2f(ah[i]));
      wh[i]  = f2bf(wv[i]);  wl_[i] = f2bf(wv[i] - bf2f(wh[i]));
    }
    *(s8v*)&Ah[row][q*8] = *(s8v*)ah;  *(s8v*)&Al[row][q*8] = *(s8v*)al_;
    *(s8v*)&Wh[row][q*8] = *(s8v*)wh;  *(s8v*)&Wl[row][q*8] = *(s8v*)wl_;
    __syncthreads();

    s8v a_hi = *(const s8v*)&Ah[w*16 + fr][fq*8];
    s8v a_lo = *(const s8v*)&Al[w*16 + fr][fq*8];
    #pragma unroll
    for (int c = 0; c < 4; ++c) {
      s8v b_hi = *(const s8v*)&Wh[c*16 + fr][fq*8];
      s8v b_lo = *(const s8v*)&Wl[c*16 + fr][fq*8];
      acc[c] = MF(a_hi, b_hi, acc[c]);
      acc[c] = MF(a_lo, b_hi, acc[c]);
      acc[c] = MF(a_hi, b_lo, acc[c]);
    }
  }

  const int orow = r0 + w * 16 + fq * 4;
  #pragma unroll
  for (int c = 0; c < 4; ++c) {
    const float bi = bias[g0 + c * 16 + fr];
    #pragma unroll
    for (int i = 0; i < 4; ++i) {
      float v = acc[c][i] + bi;
      __builtin_nontemporal_store(v, &C[(size_t)(orow + i) * G3_ + g0 + c * 16 + fr]);
    }
  }
}

// ---------------------------------------------------------------------------
// Pack W_hh into MFMA fragment order, bf16-hi only.
// ---------------------------------------------------------------------------
__global__ __launch_bounds__(64) void pack_whh(
    const float* __restrict__ Whh, unsigned short* __restrict__ Whp)
{
  const int gti = blockIdx.x, kc = blockIdx.y, lane = threadIdx.x;
  const int row = gti * 16 + (lane & 15);
  const int k0  = kc * 32 + (lane >> 4) * 8;
  const float* src = &Whh[(size_t)row * H_ + k0];
  unsigned short hi8[8];
  #pragma unroll
  for (int s = 0; s < 8; ++s) hi8[s] = f2bf(src[s]);
  const size_t o = ((size_t)(gti * 8 + kc) * 64 + lane) * 8;
  *(s8v*)&Whp[o] = *(s8v*)hi8;
}

__global__ __launch_bounds__(768) void bias2_k(
    const float* __restrict__ bih, const float* __restrict__ bhh,
    float* __restrict__ bias2)
{
  int g = threadIdx.x;
  bias2[g] = bih[g] + (g < 512 ? bhh[g] : 0.f);
}

// ---------------------------------------------------------------------------
// MFMA GRU scan v7: SINGLE barrier per step. Epilogue writes bf16(h) directly
// into the double-buffered A-frag LDS (Abuf[2]); no builder phase, no ystage.
// r,z-hi resident in 64 regs; n-hi in LDS (128KB). y stored from registers
// (NT, 4-lane 64B-line groups, off critical path). Lockstep safety: with one
// barrier/iteration all waves share the same interval -> reads hit cur,
// writes hit cur^1; __syncthreads' lgkmcnt(0) publishes writes.
// 16 WGs x 1024 threads; zero cross-WG sync, zero W stream.
// ---------------------------------------------------------------------------
__global__ __launch_bounds__(1024, 4) void gru_scan(
    const float* __restrict__ gx, const unsigned short* __restrict__ Whp,
    const float* __restrict__ bhh, float* __restrict__ hbuf,
    float* __restrict__ y, int CH, int t0c, int last)
{
  const int bid = blockIdx.x;          // 16
  const int b0  = bid * 16;
  const int tid = threadIdx.x;
  const int wid = tid >> 6, lane = tid & 63;
  const int bb = lane & 15;            // batch-local (D col)
  const int fq = lane >> 4;            // row quad (D rows 4fq..4fq+3)

  extern __shared__ unsigned short lds_[];
  unsigned short* WhN  = lds_;                 // [16 w][8 kc][512] = 128KB
  unsigned short* Abuf = lds_ + 65536;         // [2][8 kc][512] = 16KB

  const s8v* WhpV = (const s8v*)Whp;

  // resident r-hi, z-hi tiles (64 regs -> within the 128/wave cap)
  s8v whr[8], whz[8];
  #pragma unroll
  for (int kc = 0; kc < 8; ++kc) {
    whr[kc] = WhpV[((     wid) * 8 + kc) * 64 + lane];
    whz[kc] = WhpV[((16 + wid) * 8 + kc) * 64 + lane];
  }
  // n-hi tile -> LDS (each wave its own 8KB region)
  #pragma unroll
  for (int kc = 0; kc < 8; ++kc) {
    s8v v = WhpV[((32 + wid) * 8 + kc) * 64 + lane];
    *(s8v*)&WhN[(wid * 8 + kc) * 512 + lane * 8] = v;
  }

  const int u0 = 16 * wid + 4 * fq;        // own unit quad
  const f4r bhn4 = *(const f4r*)&bhh[2 * H_ + u0];

  // h state in registers
  f4r hn4 = {0.f, 0.f, 0.f, 0.f};
  if (t0c != 0) hn4 = *(const f4r*)&hbuf[(size_t)(b0 + bb) * H_ + u0];

  // static (unit,batch) -> A-frag slot mapping for this thread's h quad
  const int kcw  = wid >> 1;                              // u0 >> 5
  const int lp   = bb | (((2 * wid + (fq >> 1)) & 3) << 4);
  const int eo   = (fq & 1) * 4;                          // u0 & 7
  const int aoff = kcw * 512 + lp * 8 + eo;

  // seed buffer 0 with bf16(h0)
  {
    s4v hh;
    #pragma unroll
    for (int j = 0; j < 4; ++j) hh[j] = (short)f2bf(hn4[j]);
    *(s4v*)&Abuf[aoff] = hh;
  }

  int cur = 0;
  for (int t = 0; t < CH; ++t) {
    __syncthreads();   // bar: Abuf[cur] (and WhN at t=0) visible to all

    // gx loads (used only in epilogue; latency hides under MFMA loop)
    const float* gb = gx + ((size_t)(b0 + bb) * CH + t) * G3_;
    f4r xr4 = __builtin_nontemporal_load((const f4r*)(gb + u0));
    f4r xz4 = __builtin_nontemporal_load((const f4r*)(gb + H_ + u0));
    f4r xn4 = __builtin_nontemporal_load((const f4r*)(gb + 2 * H_ + u0));

    f4v accR = {}, accZ = {}, accN = {};
    #pragma unroll
    for (int kc = 0; kc < 8; ++kc) {
      s8v ahh = *(const s8v*)&Abuf[cur * 4096 + kc * 512 + lane * 8];
      s8v wn  = *(const s8v*)&WhN[(wid * 8 + kc) * 512 + lane * 8];
      accR = MF(whr[kc], ahh, accR);
      accZ = MF(whz[kc], ahh, accZ);
      accN = MF(wn,      ahh, accN);
    }

    // epilogue: gate math; y store from regs; publish bf16(h) to Abuf[cur^1]
    #pragma unroll
    for (int i = 0; i < 4; ++i) {
      const float r = sigm(xr4[i] + accR[i]);
      const float z = sigm(xz4[i] + accZ[i]);
      const float n = tanh_f(xn4[i] + r * (accN[i] + bhn4[i]));
      hn4[i] = (1.f - z) * n + z * hn4[i];
    }
    if (!last) {
      __builtin_nontemporal_store(
          hn4, (f4r*)&y[((size_t)(b0 + bb) * S_ + (t0c + t)) * H_ + u0]);
    }
    {
      s4v hh;
      #pragma unroll
      for (int j = 0; j < 4; ++j) hh[j] = (short)f2bf(hn4[j]);
      *(s4v*)&Abuf[(cur ^ 1) * 4096 + aoff] = hh;
    }
    cur ^= 1;
  }

  // persist h
  *(f4r*)&hbuf[(size_t)(b0 + bb) * H_ + u0] = hn4;
}

// ---------------------------------------------------------------------------
// Head: LayerNorm(h_last) -> MLP 256->32 (ReLU) -> 32->1. One wave per batch.
// ---------------------------------------------------------------------------
__global__ __launch_bounds__(64) void head_kernel(
    const float* __restrict__ hlast, const float* __restrict__ lng,
    const float* __restrict__ lnb, const float* __restrict__ W1,
    const float* __restrict__ b1, const float* __restrict__ W2,
    const float* __restrict__ b2, float* __restrict__ out)
{
  const int b = blockIdx.x;
  const int lane = threadIdx.x;
  float4 v = *(const float4*)&hlast[(size_t)b * H_ + lane * 4];
  float s = v.x + v.y + v.z + v.w;
  #pragma unroll
  for (int m = 32; m > 0; m >>= 1) s += __shfl_xor(s, m, 64);
  const float mu = s * (1.f / 256.f);
  const float dx = v.x - mu, dy = v.y - mu, dz = v.z - mu, dw = v.w - mu;
  float q = dx*dx + dy*dy + dz*dz + dw*dw;
  #pragma unroll
  for (int m = 32; m > 0; m >>= 1) q += __shfl_xor(q, m, 64);
  const float rstd = rsqrtf(q * (1.f / 256.f) + 1e-5f);

  __shared__ float ln[256];
  const int i4 = lane * 4;
  ln[i4 + 0] = dx * rstd * lng[i4 + 0] + lnb[i4 + 0];
  ln[i4 + 1] = dy * rstd * lng[i4 + 1] + lnb[i4 + 1];
  ln[i4 + 2] = dz * rstd * lng[i4 + 2] + lnb[i4 + 2];
  ln[i4 + 3] = dw * rstd * lng[i4 + 3] + lnb[i4 + 3];
  __syncthreads();

  float hd = 0.f;
  if (lane < 32) {
    const float* w = W1 + (size_t)lane * H_;
    float a = 0.f;
    for (int k = 0; k < H_; ++k) a += ln[k] * w[k];
    a += b1[lane];
    hd = fmaxf(a, 0.f) * W2[lane];
  }
  #pragma unroll
  for (int m = 16; m > 0; m >>= 1) hd += __shfl_xor(hd, m, 64);
  if (lane == 0) out[b] = hd + b2[0];
}

// ---------------------------------------------------------------------------
extern "C" void kernel_launch(void* const* d_in, const int* in_sizes, int n_in,
                              void* d_out, int out_size, void* d_ws, size_t ws_size,
                              hipStream_t stream)
{
  const float* x     = (const float*)d_in[0];
  const float* W_ih0 = (const float*)d_in[1];
  const float* W_ihr = (const float*)d_in[2];
  const float* W_hh  = (const float*)d_in[3];
  const float* b_ih  = (const float*)d_in[4];
  const float* b_hh  = (const float*)d_in[5];
  const float* lng   = (const float*)d_in[6];
  const float* lnb   = (const float*)d_in[7];
  const float* W1    = (const float*)d_in[8];
  const float* b1    = (const float*)d_in[9];
  const float* W2    = (const float*)d_in[10];
  const float* b2    = (const float*)d_in[11];
  float* out = (float*)d_out;

  const size_t y_elems   = (size_t)B_ * S_ * H_;       // 134 MB
  const size_t h_elems   = (size_t)B_ * H_;
  const size_t whp_elems = (size_t)G3_ * H_;           // bf16-hi pack

  int CH = 512;
  while (CH > 64) {
    size_t need = (y_elems + (size_t)B_ * CH * G3_ + h_elems + 768) * 4
                + whp_elems * 2 + 4096;
    if (need <= ws_size) break;
    CH >>= 1;
  }
  const int chsh = __builtin_ctz((unsigned)CH);

  float* y    = (float*)d_ws;
  float* gx   = y + y_elems;
  float* hbuf = gx + (size_t)B_ * CH * G3_;
  unsigned short* Whp = (unsigned short*)(hbuf + h_elems);
  float* bias2 = (float*)(Whp + whp_elems);

  const size_t lds_bytes = 131072 + 16384;   // 144 KiB

  for (int l = 0; l < 3; ++l) {
    const float* Wih   = (l == 0) ? W_ih0 : (W_ihr + (size_t)(l - 1) * G3_ * H_);
    const int    K     = (l == 0) ? D_ : H_;
    const float* A     = (l == 0) ? x : y;
    const float* Whh_l = W_hh + (size_t)l * G3_ * H_;
    const float* bih_l = b_ih + (size_t)l * G3_;
    const float* bhh_l = b_hh + (size_t)l * G3_;
    const int last = (l == 2) ? 1 : 0;

    bias2_k<<<1, 768, 0, stream>>>(bih_l, bhh_l, bias2);
    pack_whh<<<dim3(48, 8), 64, 0, stream>>>(Whh_l, Whp);

    for (int t0 = 0; t0 < S_; t0 += CH) {
      gemm_mfma<<<dim3(G3_ / 64, (B_ * CH) / 64), 256, 0, stream>>>(
          A, Wih, bias2, gx, K, chsh, t0);
      gru_scan<<<16, 1024, lds_bytes, stream>>>(
          gx, Whp, bhh_l, hbuf, y, CH, t0, last);
    }
  }

  head_kernel<<<256, 64, 0, stream>>>(hbuf, lng, lnb, W1, b1, W2, b2, out);
}